// Round 1
// baseline (619.617 us; speedup 1.0000x reference)
//
#include <hip/hip_runtime.h>

#define D 128
__device__ __forceinline__ float leaky(float x){ return x >= 0.f ? x : 0.01f*x; }

// Fold attention: v[0:128)=W_att^T a_src, v[128:256)=W_att^T a_dst, v[256]=b·a_src, v[257]=b·a_dst
__global__ void k_fold(const float* __restrict__ Ww, const float* __restrict__ Wb,
                       const float* __restrict__ a, float* __restrict__ v){
    int i = threadIdx.x; // 0..127
    float vs=0.f, vd=0.f;
    for (int o=0;o<D;++o){ float w = Ww[o*D+i]; vs = fmaf(w, a[o], vs); vd = fmaf(w, a[D+o], vd); }
    v[i]=vs; v[D+i]=vd;
    if(i==0){
        float cs=0.f,cd=0.f;
        for(int o=0;o<D;++o){ cs=fmaf(Wb[o],a[o],cs); cd=fmaf(Wb[o],a[D+o],cd); }
        v[256]=cs; v[257]=cd;
    }
}

// h_msg = F @ W1^T + b1.  16 nodes/block, 128 threads; thread t owns output col t.
__global__ void k_msg(const float* __restrict__ F, const float* __restrict__ W1,
                      const float* __restrict__ b1, float* __restrict__ H, int N){
    __shared__ float fs[16][D];
    int base = blockIdx.x*16;
    int t = threadIdx.x;
    for(int n=0;n<16;++n){
        int node = base+n;
        fs[n][t] = (node<N) ? F[(size_t)node*D+t] : 0.f;
    }
    __syncthreads();
    float acc[16];
    #pragma unroll
    for(int n=0;n<16;++n) acc[n]=0.f;
    const float* wrow = W1 + (size_t)t*D;
    for(int i=0;i<D;++i){
        float w = wrow[i];
        #pragma unroll
        for(int n=0;n<16;++n) acc[n] = fmaf(w, fs[n][i], acc[n]);
    }
    float bb = b1[t];
    for(int n=0;n<16;++n){
        int node = base+n;
        if(node<N) H[(size_t)node*D+t] = acc[n]+bb;
    }
}

// per-node attention scalars ss/sd; one wave per node
__global__ void k_scal(const float* __restrict__ F, const float* __restrict__ v,
                       float* __restrict__ ss, float* __restrict__ sd, int N){
    int wave = threadIdx.x >> 6, lane = threadIdx.x & 63;
    int node = blockIdx.x*4 + wave;
    if(node>=N) return;
    float2 f  = *(const float2*)(F + (size_t)node*D + lane*2);
    float2 vs = *(const float2*)(v + lane*2);
    float2 vd = *(const float2*)(v + D + lane*2);
    float s1 = f.x*vs.x + f.y*vs.y;
    float s2 = f.x*vd.x + f.y*vd.y;
    #pragma unroll
    for(int o=1;o<64;o<<=1){ s1 += __shfl_xor(s1,o); s2 += __shfl_xor(s2,o); }
    if(lane==0){ ss[node]=s1+v[256]; sd[node]=s2+v[257]; }
}

__global__ void k_hist(const int* __restrict__ dst, unsigned* __restrict__ cnt, int E){
    int e = blockIdx.x*blockDim.x + threadIdx.x;
    if(e<E) atomicAdd(&cnt[dst[e]], 1u);
}

// exclusive scan, 1024 elems/block; block prefix computed by redundant reduce (no inter-block dep)
__global__ void k_scan(const unsigned* __restrict__ cnt, unsigned* __restrict__ off, int N){
    int b = blockIdx.x, t = threadIdx.x; // 256 threads
    int base = b*1024;
    __shared__ unsigned lds[256];
    unsigned s = 0;
    for(int j=t; j<base; j+=256) s += cnt[j];
    #pragma unroll
    for(int o=1;o<64;o<<=1) s += __shfl_xor(s,o);
    if((t&63)==0) lds[t>>6] = s;
    __syncthreads();
    unsigned prefix = lds[0]+lds[1]+lds[2]+lds[3];
    __syncthreads();
    unsigned v[4]; unsigned tsum=0;
    #pragma unroll
    for(int k=0;k<4;++k){ int i = base + t*4 + k; v[k] = (i<N)?cnt[i]:0u; tsum += v[k]; }
    unsigned x = tsum;
    #pragma unroll
    for(int o=1;o<64;o<<=1){ unsigned y = __shfl_up(x,(unsigned)o); if((t&63)>=o) x += y; }
    if((t&63)==63) lds[t>>6] = x;
    __syncthreads();
    unsigned waveoff = 0;
    for(int w=0; w<(t>>6); ++w) waveoff += lds[w];
    unsigned run = prefix + waveoff + (x - tsum);
    #pragma unroll
    for(int k=0;k<4;++k){
        int i = base + t*4 + k;
        if(i<N) off[i] = run;
        else if(i==N) off[N] = run;
        run += v[k];
    }
}

__global__ void k_scatter(const int* __restrict__ src, const int* __restrict__ dst,
                          const unsigned* __restrict__ off, unsigned* __restrict__ cur,
                          unsigned* __restrict__ esrc, int E){
    int e = blockIdx.x*blockDim.x + threadIdx.x;
    if(e>=E) return;
    int d = dst[e];
    unsigned p = off[d] + atomicAdd(&cur[d], 1u);
    esrc[p] = (unsigned)src[e];
}

// fused: per destination node, weighted gather of h_msg with online denominator
__global__ void k_gather(const unsigned* __restrict__ off, const unsigned* __restrict__ esrc,
                         const float* __restrict__ ss, const float* __restrict__ sd,
                         const float* __restrict__ H, float* __restrict__ out, int N){
    int wave = threadIdx.x>>6, lane = threadIdx.x&63;
    int d = blockIdx.x*4 + wave;
    if(d>=N) return;
    unsigned kb = off[d], ke = off[d+1];
    float sdd = sd[d];
    float ax=0.f, ay=0.f, denom=0.f;
    for(unsigned k=kb;k<ke;++k){
        unsigned s = esrc[k];
        float w = __expf(leaky(ss[s]+sdd));
        float2 h = *(const float2*)(H + (size_t)s*D + lane*2);
        ax = fmaf(w,h.x,ax); ay = fmaf(w,h.y,ay);
        denom += w;
    }
    float inv = 1.f/(denom+1e-9f);
    float2 r; r.x = ax*inv; r.y = ay*inv;
    *(float2*)(out + (size_t)d*D + lane*2) = r;
}

// out = leaky(f + h + (f*h)@W2^T + b2); h currently staged in `out`, overwritten in place.
__global__ void k_final(const float* __restrict__ F, const float* __restrict__ W2,
                        const float* __restrict__ b2, float* __restrict__ out, int N){
    __shared__ float p[16][D];
    __shared__ float t1[16][D];
    int base = blockIdx.x*16;
    int t = threadIdx.x;
    for(int n=0;n<16;++n){
        int node = base+n;
        float f=0.f,h=0.f;
        if(node<N){ f = F[(size_t)node*D+t]; h = out[(size_t)node*D+t]; }
        p[n][t] = f*h; t1[n][t] = f+h;
    }
    __syncthreads();
    float acc[16];
    #pragma unroll
    for(int n=0;n<16;++n) acc[n]=0.f;
    const float* wrow = W2 + (size_t)t*D;
    for(int i=0;i<D;++i){
        float w = wrow[i];
        #pragma unroll
        for(int n=0;n<16;++n) acc[n] = fmaf(w, p[n][i], acc[n]);
    }
    float bb = b2[t];
    for(int n=0;n<16;++n){
        int node = base+n;
        if(node<N) out[(size_t)node*D+t] = leaky(t1[n][t] + acc[n] + bb);
    }
}

extern "C" void kernel_launch(void* const* d_in, const int* in_sizes, int n_in,
                              void* d_out, int out_size, void* d_ws, size_t ws_size,
                              hipStream_t stream) {
    const int*   idx  = (const int*)  d_in[0];   // (2,E)
    const float* F    = (const float*)d_in[1];   // (N,128)
    const float* Waw  = (const float*)d_in[3];
    const float* Wab  = (const float*)d_in[4];
    const float* W1w  = (const float*)d_in[5];
    const float* W1b  = (const float*)d_in[6];
    const float* W2w  = (const float*)d_in[7];
    const float* W2b  = (const float*)d_in[8];
    const float* a    = (const float*)d_in[9];
    float* out = (float*)d_out;

    const int E = in_sizes[0]/2;
    const int N = in_sizes[1]/D;
    const int* srcp = idx;
    const int* dstp = idx + E;

    float* ws = (float*)d_ws;
    float*    h_msg = ws;                       // N*D
    float*    ss    = h_msg + (size_t)N*D;      // N
    float*    sd    = ss + N;                   // N
    float*    v     = sd + N;                   // 320
    unsigned* cnt   = (unsigned*)(v + 320);     // N
    unsigned* cur   = cnt + N;                  // N
    unsigned* offs  = cur + N;                  // N+1
    unsigned* esrc  = offs + (N+2);             // E

    hipMemsetAsync(cnt, 0, (size_t)2*N*sizeof(unsigned), stream);

    k_fold   <<<1, 128, 0, stream>>>(Waw, Wab, a, v);
    k_msg    <<<(N+15)/16, 128, 0, stream>>>(F, W1w, W1b, h_msg, N);
    k_scal   <<<(N+3)/4, 256, 0, stream>>>(F, v, ss, sd, N);
    k_hist   <<<(E+255)/256, 256, 0, stream>>>(dstp, cnt, E);
    k_scan   <<<(N+1+1023)/1024, 256, 0, stream>>>(cnt, offs, N);
    k_scatter<<<(E+255)/256, 256, 0, stream>>>(srcp, dstp, offs, cur, esrc, E);
    k_gather <<<(N+3)/4, 256, 0, stream>>>(offs, esrc, ss, sd, h_msg, out, N);
    k_final  <<<(N+15)/16, 128, 0, stream>>>(F, W2w, W2b, out, N);
}

// Round 2
// 456.746 us; speedup vs baseline: 1.3566x; 1.3566x over previous
//
#include <hip/hip_runtime.h>

#define D 128
typedef __attribute__((ext_vector_type(8))) short short8;
typedef __attribute__((ext_vector_type(4))) float f32x4;

__device__ __forceinline__ float leaky(float x){ return x >= 0.f ? x : 0.01f*x; }
__device__ __forceinline__ unsigned short f2bf(float x){
    unsigned u = __float_as_uint(x);
    u = (u + 0x7fffu + ((u>>16)&1u)) >> 16;
    return (unsigned short)u;
}

// Fold attention: v[0:128)=W_att^T a_src, v[128:256)=W_att^T a_dst, v[256]=b·a_src, v[257]=b·a_dst
__global__ void k_fold(const float* __restrict__ Ww, const float* __restrict__ Wb,
                       const float* __restrict__ a, float* __restrict__ v){
    int i = threadIdx.x; // 0..127
    float vs=0.f, vd=0.f;
    for (int o=0;o<D;++o){ float w = Ww[o*D+i]; vs = fmaf(w, a[o], vs); vd = fmaf(w, a[D+o], vd); }
    v[i]=vs; v[D+i]=vd;
    if(i==0){
        float cs=0.f,cd=0.f;
        for(int o=0;o<D;++o){ cs=fmaf(Wb[o],a[o],cs); cd=fmaf(Wb[o],a[D+o],cd); }
        v[256]=cs; v[257]=cd;
    }
}

// convert W1,W2 to bf16
__global__ void k_wconv(const float* __restrict__ W1, const float* __restrict__ W2,
                        unsigned short* __restrict__ W1b, unsigned short* __restrict__ W2b){
    int i = blockIdx.x*256 + threadIdx.x; // 0..32767
    if(i < 16384) W1b[i] = f2bf(W1[i]);
    else          W2b[i-16384] = f2bf(W2[i-16384]);
}

// per-node attention scalars ss/sd; one wave per node
__global__ void k_scal(const float* __restrict__ F, const float* __restrict__ v,
                       float* __restrict__ ss, float* __restrict__ sd, int N){
    int wave = threadIdx.x >> 6, lane = threadIdx.x & 63;
    int node = blockIdx.x*4 + wave;
    if(node>=N) return;
    float2 f  = *(const float2*)(F + (size_t)node*D + lane*2);
    float2 vs = *(const float2*)(v + lane*2);
    float2 vd = *(const float2*)(v + D + lane*2);
    float s1 = f.x*vs.x + f.y*vs.y;
    float s2 = f.x*vd.x + f.y*vd.y;
    #pragma unroll
    for(int o=1;o<64;o<<=1){ s1 += __shfl_xor(s1,o); s2 += __shfl_xor(s2,o); }
    if(lane==0){ ss[node]=s1+v[256]; sd[node]=s2+v[257]; }
}

__global__ void k_hist(const int* __restrict__ dst, unsigned* __restrict__ cnt, int E){
    int e = blockIdx.x*blockDim.x + threadIdx.x;
    if(e<E) atomicAdd(&cnt[dst[e]], 1u);
}

// exclusive scan, 1024 elems/block; block prefix by redundant reduce (no inter-block dep)
__global__ void k_scan(const unsigned* __restrict__ cnt, unsigned* __restrict__ off, int N){
    int b = blockIdx.x, t = threadIdx.x; // 256 threads
    int base = b*1024;
    __shared__ unsigned lds[256];
    unsigned s = 0;
    for(int j=t; j<base; j+=256) s += cnt[j];
    #pragma unroll
    for(int o=1;o<64;o<<=1) s += __shfl_xor(s,o);
    if((t&63)==0) lds[t>>6] = s;
    __syncthreads();
    unsigned prefix = lds[0]+lds[1]+lds[2]+lds[3];
    __syncthreads();
    unsigned v[4]; unsigned tsum=0;
    #pragma unroll
    for(int k=0;k<4;++k){ int i = base + t*4 + k; v[k] = (i<N)?cnt[i]:0u; tsum += v[k]; }
    unsigned x = tsum;
    #pragma unroll
    for(int o=1;o<64;o<<=1){ unsigned y = __shfl_up(x,(unsigned)o); if((t&63)>=o) x += y; }
    if((t&63)==63) lds[t>>6] = x;
    __syncthreads();
    unsigned waveoff = 0;
    for(int w=0; w<(t>>6); ++w) waveoff += lds[w];
    unsigned run = prefix + waveoff + (x - tsum);
    #pragma unroll
    for(int k=0;k<4;++k){
        int i = base + t*4 + k;
        if(i<N) off[i] = run;
        else if(i==N) off[N] = run;
        run += v[k];
    }
}

__global__ void k_scatter(const int* __restrict__ src, const int* __restrict__ dst,
                          const unsigned* __restrict__ off, unsigned* __restrict__ cur,
                          unsigned* __restrict__ esrc, int E){
    int e = blockIdx.x*blockDim.x + threadIdx.x;
    if(e>=E) return;
    int d = dst[e];
    unsigned p = off[d] + atomicAdd(&cur[d], 1u);
    esrc[p] = (unsigned)src[e];
}

// H_perm = bf16(F @ W1^T + b1), row layout permuted: c' = (c&15)*8 + (c>>4)
// MFMA 16x16x32 bf16. W1 register-resident (32 frags). One wave per 16-row tile.
__global__ __launch_bounds__(256) void k_msg(const float* __restrict__ F,
        const unsigned short* __restrict__ W1b, const float* __restrict__ b1,
        unsigned short* __restrict__ Hp, int N){
    const int lane = threadIdx.x & 63;
    const int wid  = blockIdx.x*4 + (threadIdx.x>>6);
    const int nw   = gridDim.x*4;
    const int t = lane & 15, g = lane >> 4;
    // B frags: B[k][n] = W1[n][k]; lane: n = j*16+t, k = kk*32 + g*8 + i
    short8 wf[4][8];
    #pragma unroll
    for(int kk=0;kk<4;++kk)
      #pragma unroll
      for(int j=0;j<8;++j)
        wf[kk][j] = *(const short8*)(W1b + (size_t)(j*16+t)*D + kk*32 + g*8);
    float bb[8];
    #pragma unroll
    for(int j=0;j<8;++j) bb[j] = b1[j*16+t];
    const int Mt = (N+15)>>4;
    for(int rt = wid; rt < Mt; rt += nw){
        int row = rt*16 + t; if(row>=N) row = N-1;
        const float* fr = F + (size_t)row*D + g*8;
        f32x4 acc[8];
        #pragma unroll
        for(int j=0;j<8;++j) acc[j] = (f32x4){0.f,0.f,0.f,0.f};
        #pragma unroll
        for(int kk=0;kk<4;++kk){
            f32x4 lo = *(const f32x4*)(fr + kk*32);
            f32x4 hi = *(const f32x4*)(fr + kk*32 + 4);
            short8 af;
            af[0]=(short)f2bf(lo[0]); af[1]=(short)f2bf(lo[1]);
            af[2]=(short)f2bf(lo[2]); af[3]=(short)f2bf(lo[3]);
            af[4]=(short)f2bf(hi[0]); af[5]=(short)f2bf(hi[1]);
            af[6]=(short)f2bf(hi[2]); af[7]=(short)f2bf(hi[3]);
            #pragma unroll
            for(int j=0;j<8;++j)
                acc[j] = __builtin_amdgcn_mfma_f32_16x16x32_bf16(af, wf[kk][j], acc[j], 0,0,0);
        }
        // store: lane holds col j*16+t, rows rt*16 + g*4 + r; permuted c' = t*8 + j
        #pragma unroll
        for(int r=0;r<4;++r){
            int rr = rt*16 + g*4 + r;
            if(rr < N){
                short8 h;
                #pragma unroll
                for(int j=0;j<8;++j) h[j] = (short)f2bf(acc[j][r] + bb[j]);
                *(short8*)(Hp + (size_t)rr*D + t*8) = h;
            }
        }
    }
}

// fused gather: per dest node, weighted sum of permuted bf16 H rows with online denom
__global__ void k_gather(const unsigned* __restrict__ off, const unsigned* __restrict__ esrc,
                         const float* __restrict__ ss, const float* __restrict__ sd,
                         const unsigned short* __restrict__ Hp, float* __restrict__ out, int N){
    int wv = threadIdx.x>>6, l = threadIdx.x&63;
    int d = blockIdx.x*4 + wv;
    if(d>=N) return;
    unsigned kb = off[d], ke = off[d+1];
    float sdd = sd[d];
    float a0=0.f, a1=0.f, den=0.f;
    for(unsigned k=kb;k<ke;++k){
        unsigned s = esrc[k];
        float w = __expf(leaky(ss[s]+sdd));
        unsigned u = *(const unsigned*)(Hp + (size_t)s*D + 2*l);
        float f0 = __uint_as_float(u<<16);
        float f1 = __uint_as_float(u & 0xffff0000u);
        a0 = fmaf(w,f0,a0); a1 = fmaf(w,f1,a1); den += w;
    }
    float inv = 1.f/(den+1e-9f);
    int c0 = (l&3)*32 + (l>>2);   // true col of c'=2l ; c'=2l+1 -> c0+16
    out[(size_t)d*D + c0]      = a0*inv;
    out[(size_t)d*D + c0 + 16] = a1*inv;
}

// out = leaky(f + h + (f*h)@W2^T + b2), in place on out (h currently in out)
__global__ __launch_bounds__(256) void k_final(const float* __restrict__ F,
        const unsigned short* __restrict__ W2b, const float* __restrict__ b2,
        float* __restrict__ out, int N){
    const int lane = threadIdx.x & 63;
    const int wid  = blockIdx.x*4 + (threadIdx.x>>6);
    const int nw   = gridDim.x*4;
    const int t = lane & 15, g = lane >> 4;
    short8 wf[4][8];
    #pragma unroll
    for(int kk=0;kk<4;++kk)
      #pragma unroll
      for(int j=0;j<8;++j)
        wf[kk][j] = *(const short8*)(W2b + (size_t)(j*16+t)*D + kk*32 + g*8);
    float bb[8];
    #pragma unroll
    for(int j=0;j<8;++j) bb[j] = b2[j*16+t];
    const int Mt = (N+15)>>4;
    for(int rt = wid; rt < Mt; rt += nw){
        int row = rt*16 + t; if(row>=N) row = N-1;
        const float* fr = F   + (size_t)row*D + g*8;
        const float* hr = out + (size_t)row*D + g*8;
        f32x4 acc[8];
        #pragma unroll
        for(int j=0;j<8;++j) acc[j] = (f32x4){0.f,0.f,0.f,0.f};
        #pragma unroll
        for(int kk=0;kk<4;++kk){
            f32x4 flo = *(const f32x4*)(fr + kk*32);
            f32x4 fhi = *(const f32x4*)(fr + kk*32 + 4);
            f32x4 hlo = *(const f32x4*)(hr + kk*32);
            f32x4 hhi = *(const f32x4*)(hr + kk*32 + 4);
            short8 af;
            af[0]=(short)f2bf(flo[0]*hlo[0]); af[1]=(short)f2bf(flo[1]*hlo[1]);
            af[2]=(short)f2bf(flo[2]*hlo[2]); af[3]=(short)f2bf(flo[3]*hlo[3]);
            af[4]=(short)f2bf(fhi[0]*hhi[0]); af[5]=(short)f2bf(fhi[1]*hhi[1]);
            af[6]=(short)f2bf(fhi[2]*hhi[2]); af[7]=(short)f2bf(fhi[3]*hhi[3]);
            #pragma unroll
            for(int j=0;j<8;++j)
                acc[j] = __builtin_amdgcn_mfma_f32_16x16x32_bf16(af, wf[kk][j], acc[j], 0,0,0);
        }
        // epilogue: re-read f,h at D-layout (L1-hot), t1 = f+h, out = leaky(t1+acc+b2)
        #pragma unroll
        for(int r=0;r<4;++r){
            int rr = rt*16 + g*4 + r;
            if(rr < N){
                #pragma unroll
                for(int j=0;j<8;++j){
                    int c = j*16 + t;
                    float f = F[(size_t)rr*D + c];
                    float h = out[(size_t)rr*D + c];
                    float val = f + h + acc[j][r] + bb[j];
                    out[(size_t)rr*D + c] = leaky(val);
                }
            }
        }
    }
}

extern "C" void kernel_launch(void* const* d_in, const int* in_sizes, int n_in,
                              void* d_out, int out_size, void* d_ws, size_t ws_size,
                              hipStream_t stream) {
    const int*   idx  = (const int*)  d_in[0];   // (2,E)
    const float* F    = (const float*)d_in[1];   // (N,128)
    const float* Waw  = (const float*)d_in[3];
    const float* Wab  = (const float*)d_in[4];
    const float* W1w  = (const float*)d_in[5];
    const float* W1b  = (const float*)d_in[6];
    const float* W2w  = (const float*)d_in[7];
    const float* W2b  = (const float*)d_in[8];
    const float* a    = (const float*)d_in[9];
    float* out = (float*)d_out;

    const int E = in_sizes[0]/2;
    const int N = in_sizes[1]/D;
    const int* srcp = idx;
    const int* dstp = idx + E;

    unsigned short* Hp  = (unsigned short*)d_ws;          // N*128 bf16 (permuted rows)
    unsigned short* W1c = Hp + (size_t)N*D;                // 16384
    unsigned short* W2c = W1c + 16384;                     // 16384
    float*    ss   = (float*)(W2c + 16384);                // N
    float*    sd   = ss + N;                               // N
    float*    v    = sd + N;                               // 320
    unsigned* cnt  = (unsigned*)(v + 320);                 // N
    unsigned* cur  = cnt + N;                              // N
    unsigned* offs = cur + N;                              // N+2
    unsigned* esrc = offs + (N+2);                         // E

    hipMemsetAsync(cnt, 0, (size_t)2*N*sizeof(unsigned), stream);

    k_fold   <<<1, 128, 0, stream>>>(Waw, Wab, a, v);
    k_wconv  <<<128, 256, 0, stream>>>(W1w, W2w, W1c, W2c);
    k_msg    <<<512, 256, 0, stream>>>(F, W1c, W1b, Hp, N);
    k_scal   <<<(N+3)/4, 256, 0, stream>>>(F, v, ss, sd, N);
    k_hist   <<<(E+255)/256, 256, 0, stream>>>(dstp, cnt, E);
    k_scan   <<<(N+1+1023)/1024, 256, 0, stream>>>(cnt, offs, N);
    k_scatter<<<(E+255)/256, 256, 0, stream>>>(srcp, dstp, offs, cur, esrc, E);
    k_gather <<<(N+3)/4, 256, 0, stream>>>(offs, esrc, ss, sd, Hp, out, N);
    k_final  <<<512, 256, 0, stream>>>(F, W2c, W2b, out, N);
}

// Round 3
// 357.381 us; speedup vs baseline: 1.7338x; 1.2780x over previous
//
#include <hip/hip_runtime.h>

#define D 128
typedef __attribute__((ext_vector_type(8))) short short8;
typedef __attribute__((ext_vector_type(4))) float f32x4;

__device__ __forceinline__ float leaky(float x){ return x >= 0.f ? x : 0.01f*x; }
__device__ __forceinline__ unsigned short f2bf(float x){
    unsigned u = __float_as_uint(x);
    u = (u + 0x7fffu + ((u>>16)&1u)) >> 16;
    return (unsigned short)u;
}

// Fold attention vectors + convert W1/W2 to bf16 (block 0 does fold, rest convert)
__global__ void k_prep(const float* __restrict__ Ww, const float* __restrict__ Wb,
                       const float* __restrict__ a, float* __restrict__ v,
                       const float* __restrict__ W1, const float* __restrict__ W2,
                       unsigned short* __restrict__ W1b, unsigned short* __restrict__ W2b){
    int b = blockIdx.x;
    if(b < 64){
        int i = b*256 + threadIdx.x; // 0..16383
        W1b[i] = f2bf(W1[i]);
        W2b[i] = f2bf(W2[i]);
        return;
    }
    int i = threadIdx.x; if(i >= 128) return;
    float vs=0.f, vd=0.f;
    for (int o=0;o<D;++o){ float w = Ww[o*D+i]; vs = fmaf(w, a[o], vs); vd = fmaf(w, a[D+o], vd); }
    v[i]=vs; v[D+i]=vd;
    if(i==0){
        float cs=0.f,cd=0.f;
        for(int o=0;o<D;++o){ cs=fmaf(Wb[o],a[o],cs); cd=fmaf(Wb[o],a[D+o],cd); }
        v[256]=cs; v[257]=cd;
    }
}

// per-node attention scalars ss/sd; one wave per node
__global__ void k_scal(const float* __restrict__ F, const float* __restrict__ v,
                       float* __restrict__ ss, float* __restrict__ sd, int N){
    int wave = threadIdx.x >> 6, lane = threadIdx.x & 63;
    int node = blockIdx.x*4 + wave;
    if(node>=N) return;
    float2 f  = *(const float2*)(F + (size_t)node*D + lane*2);
    float2 vs = *(const float2*)(v + lane*2);
    float2 vd = *(const float2*)(v + D + lane*2);
    float s1 = f.x*vs.x + f.y*vs.y;
    float s2 = f.x*vd.x + f.y*vd.y;
    #pragma unroll
    for(int o=1;o<64;o<<=1){ s1 += __shfl_xor(s1,o); s2 += __shfl_xor(s2,o); }
    if(lane==0){ ss[node]=s1+v[256]; sd[node]=s2+v[257]; }
}

__global__ void k_hist(const int* __restrict__ dst, unsigned* __restrict__ cnt, int E){
    int e = blockIdx.x*blockDim.x + threadIdx.x;
    if(e<E) atomicAdd(&cnt[dst[e]], 1u);
}

// exclusive scan, 1024 elems/block; block prefix by redundant reduce (no inter-block dep)
__global__ void k_scan(const unsigned* __restrict__ cnt, unsigned* __restrict__ off, int N){
    int b = blockIdx.x, t = threadIdx.x; // 256 threads
    int base = b*1024;
    __shared__ unsigned lds[256];
    unsigned s = 0;
    for(int j=t; j<base; j+=256) s += cnt[j];
    #pragma unroll
    for(int o=1;o<64;o<<=1) s += __shfl_xor(s,o);
    if((t&63)==0) lds[t>>6] = s;
    __syncthreads();
    unsigned prefix = lds[0]+lds[1]+lds[2]+lds[3];
    __syncthreads();
    unsigned v[4]; unsigned tsum=0;
    #pragma unroll
    for(int k=0;k<4;++k){ int i = base + t*4 + k; v[k] = (i<N)?cnt[i]:0u; tsum += v[k]; }
    unsigned x = tsum;
    #pragma unroll
    for(int o=1;o<64;o<<=1){ unsigned y = __shfl_up(x,(unsigned)o); if((t&63)>=o) x += y; }
    if((t&63)==63) lds[t>>6] = x;
    __syncthreads();
    unsigned waveoff = 0;
    for(int w=0; w<(t>>6); ++w) waveoff += lds[w];
    unsigned run = prefix + waveoff + (x - tsum);
    #pragma unroll
    for(int k=0;k<4;++k){
        int i = base + t*4 + k;
        if(i<N) off[i] = run;
        else if(i==N) off[N] = run;
        run += v[k];
    }
}

// scatter edges into CSR slots, packing (src, exp-weight) per edge
__global__ void k_scatter(const int* __restrict__ src, const int* __restrict__ dst,
                          const unsigned* __restrict__ off, unsigned* __restrict__ cur,
                          const float* __restrict__ ss, const float* __restrict__ sd,
                          uint2* __restrict__ ew, int E){
    int e = blockIdx.x*blockDim.x + threadIdx.x;
    if(e>=E) return;
    int d = dst[e];
    int s = src[e];
    float w = __expf(leaky(ss[s] + sd[d]));
    unsigned p = off[d] + atomicAdd(&cur[d], 1u);
    ew[p] = make_uint2((unsigned)s, __float_as_uint(w));
}

// H_perm = bf16(F @ W1^T + b1), row layout permuted: c' = (c&15)*8 + (c>>4)
__global__ __launch_bounds__(256) void k_msg(const float* __restrict__ F,
        const unsigned short* __restrict__ W1b, const float* __restrict__ b1,
        unsigned short* __restrict__ Hp, int N){
    const int lane = threadIdx.x & 63;
    const int wid  = blockIdx.x*4 + (threadIdx.x>>6);
    const int nw   = gridDim.x*4;
    const int t = lane & 15, g = lane >> 4;
    short8 wf[4][8];
    #pragma unroll
    for(int kk=0;kk<4;++kk)
      #pragma unroll
      for(int j=0;j<8;++j)
        wf[kk][j] = *(const short8*)(W1b + (size_t)(j*16+t)*D + kk*32 + g*8);
    float bb[8];
    #pragma unroll
    for(int j=0;j<8;++j) bb[j] = b1[j*16+t];
    const int Mt = (N+15)>>4;
    for(int rt = wid; rt < Mt; rt += nw){
        int row = rt*16 + t; if(row>=N) row = N-1;
        const float* fr = F + (size_t)row*D + g*8;
        f32x4 acc[8];
        #pragma unroll
        for(int j=0;j<8;++j) acc[j] = (f32x4){0.f,0.f,0.f,0.f};
        #pragma unroll
        for(int kk=0;kk<4;++kk){
            f32x4 lo = *(const f32x4*)(fr + kk*32);
            f32x4 hi = *(const f32x4*)(fr + kk*32 + 4);
            short8 af;
            af[0]=(short)f2bf(lo[0]); af[1]=(short)f2bf(lo[1]);
            af[2]=(short)f2bf(lo[2]); af[3]=(short)f2bf(lo[3]);
            af[4]=(short)f2bf(hi[0]); af[5]=(short)f2bf(hi[1]);
            af[6]=(short)f2bf(hi[2]); af[7]=(short)f2bf(hi[3]);
            #pragma unroll
            for(int j=0;j<8;++j)
                acc[j] = __builtin_amdgcn_mfma_f32_16x16x32_bf16(af, wf[kk][j], acc[j], 0,0,0);
        }
        #pragma unroll
        for(int r=0;r<4;++r){
            int rr = rt*16 + g*4 + r;
            if(rr < N){
                short8 h;
                #pragma unroll
                for(int j=0;j<8;++j) h[j] = (short)f2bf(acc[j][r] + bb[j]);
                *(short8*)(Hp + (size_t)rr*D + t*8) = h;
            }
        }
    }
}

// fused gather: 4 edges/iter, 16 lanes/edge, 16B per lane; online denominator.
__global__ __launch_bounds__(256) void k_gather(const unsigned* __restrict__ off,
        const uint2* __restrict__ ew, const unsigned short* __restrict__ Hp,
        float* __restrict__ out, int N){
    const int wv = threadIdx.x>>6, l = threadIdx.x&63;
    const int d = blockIdx.x*4 + wv;
    if(d>=N) return;
    const int g = l>>4, t = l&15;
    const unsigned kb = off[d], ke = off[d+1];
    float acc[8];
    #pragma unroll
    for(int j=0;j<8;++j) acc[j]=0.f;
    float den = 0.f;

    unsigned e = kb + g;
    bool v = e < ke;
    uint2 sw = make_uint2(0u,0u);
    uint4 u  = make_uint4(0u,0u,0u,0u);
    if(v){
        sw = ew[e];
        u  = *(const uint4*)(Hp + (size_t)sw.x*D + t*8);
    }
    while(v){
        unsigned e2 = e + 4;
        bool v2 = e2 < ke;
        uint2 sw2 = make_uint2(0u,0u);
        uint4 u2  = make_uint4(0u,0u,0u,0u);
        if(v2){
            sw2 = ew[e2];
            u2  = *(const uint4*)(Hp + (size_t)sw2.x*D + t*8);
        }
        float w = __uint_as_float(sw.y);
        acc[0] = fmaf(w, __uint_as_float(u.x<<16),        acc[0]);
        acc[1] = fmaf(w, __uint_as_float(u.x&0xffff0000u),acc[1]);
        acc[2] = fmaf(w, __uint_as_float(u.y<<16),        acc[2]);
        acc[3] = fmaf(w, __uint_as_float(u.y&0xffff0000u),acc[3]);
        acc[4] = fmaf(w, __uint_as_float(u.z<<16),        acc[4]);
        acc[5] = fmaf(w, __uint_as_float(u.z&0xffff0000u),acc[5]);
        acc[6] = fmaf(w, __uint_as_float(u.w<<16),        acc[6]);
        acc[7] = fmaf(w, __uint_as_float(u.w&0xffff0000u),acc[7]);
        den += w;
        v = v2; sw = sw2; u = u2; e = e2;
    }
    // combine the 4 edge-groups
    #pragma unroll
    for(int j=0;j<8;++j){
        acc[j] += __shfl_xor(acc[j],16);
        acc[j] += __shfl_xor(acc[j],32);
    }
    den += __shfl_xor(den,16);
    den += __shfl_xor(den,32);
    float inv = 1.f/(den + 1e-9f);
    // lane holds c' = t*8 + j; write true cols c = g*32+t (j=g*2) and c+16 (j=g*2+1)
    int c = g*32 + t;
    out[(size_t)d*D + c]      = acc[g*2]  * inv;
    out[(size_t)d*D + c + 16] = acc[g*2+1]* inv;
}

// out = leaky(f + h + (f*h)@W2^T + b2), in place on out (h currently in out)
__global__ __launch_bounds__(256) void k_final(const float* __restrict__ F,
        const unsigned short* __restrict__ W2b, const float* __restrict__ b2,
        float* __restrict__ out, int N){
    const int lane = threadIdx.x & 63;
    const int wid  = blockIdx.x*4 + (threadIdx.x>>6);
    const int nw   = gridDim.x*4;
    const int t = lane & 15, g = lane >> 4;
    short8 wf[4][8];
    #pragma unroll
    for(int kk=0;kk<4;++kk)
      #pragma unroll
      for(int j=0;j<8;++j)
        wf[kk][j] = *(const short8*)(W2b + (size_t)(j*16+t)*D + kk*32 + g*8);
    float bb[8];
    #pragma unroll
    for(int j=0;j<8;++j) bb[j] = b2[j*16+t];
    const int Mt = (N+15)>>4;
    for(int rt = wid; rt < Mt; rt += nw){
        int row = rt*16 + t; if(row>=N) row = N-1;
        const float* fr = F   + (size_t)row*D + g*8;
        const float* hr = out + (size_t)row*D + g*8;
        f32x4 acc[8];
        #pragma unroll
        for(int j=0;j<8;++j) acc[j] = (f32x4){0.f,0.f,0.f,0.f};
        #pragma unroll
        for(int kk=0;kk<4;++kk){
            f32x4 flo = *(const f32x4*)(fr + kk*32);
            f32x4 fhi = *(const f32x4*)(fr + kk*32 + 4);
            f32x4 hlo = *(const f32x4*)(hr + kk*32);
            f32x4 hhi = *(const f32x4*)(hr + kk*32 + 4);
            short8 af;
            af[0]=(short)f2bf(flo[0]*hlo[0]); af[1]=(short)f2bf(flo[1]*hlo[1]);
            af[2]=(short)f2bf(flo[2]*hlo[2]); af[3]=(short)f2bf(flo[3]*hlo[3]);
            af[4]=(short)f2bf(fhi[0]*hhi[0]); af[5]=(short)f2bf(fhi[1]*hhi[1]);
            af[6]=(short)f2bf(fhi[2]*hhi[2]); af[7]=(short)f2bf(fhi[3]*hhi[3]);
            #pragma unroll
            for(int j=0;j<8;++j)
                acc[j] = __builtin_amdgcn_mfma_f32_16x16x32_bf16(af, wf[kk][j], acc[j], 0,0,0);
        }
        #pragma unroll
        for(int r=0;r<4;++r){
            int rr = rt*16 + g*4 + r;
            if(rr < N){
                #pragma unroll
                for(int j=0;j<8;++j){
                    int c = j*16 + t;
                    float f = F[(size_t)rr*D + c];
                    float h = out[(size_t)rr*D + c];
                    float val = f + h + acc[j][r] + bb[j];
                    out[(size_t)rr*D + c] = leaky(val);
                }
            }
        }
    }
}

extern "C" void kernel_launch(void* const* d_in, const int* in_sizes, int n_in,
                              void* d_out, int out_size, void* d_ws, size_t ws_size,
                              hipStream_t stream) {
    const int*   idx  = (const int*)  d_in[0];   // (2,E)
    const float* F    = (const float*)d_in[1];   // (N,128)
    const float* Waw  = (const float*)d_in[3];
    const float* Wab  = (const float*)d_in[4];
    const float* W1w  = (const float*)d_in[5];
    const float* W1b  = (const float*)d_in[6];
    const float* W2w  = (const float*)d_in[7];
    const float* W2b  = (const float*)d_in[8];
    const float* a    = (const float*)d_in[9];
    float* out = (float*)d_out;

    const int E = in_sizes[0]/2;
    const int N = in_sizes[1]/D;
    const int* srcp = idx;
    const int* dstp = idx + E;

    unsigned short* Hp  = (unsigned short*)d_ws;           // N*128 bf16 (permuted rows)
    unsigned short* W1c = Hp + (size_t)N*D;                // 16384
    unsigned short* W2c = W1c + 16384;                     // 16384
    float*    ss   = (float*)(W2c + 16384);                // N
    float*    sd   = ss + N;                               // N
    float*    v    = sd + N;                               // 320
    unsigned* cnt  = (unsigned*)(v + 320);                 // N
    unsigned* cur  = cnt + N;                              // N
    unsigned* offs = cur + N;                              // N+4
    uint2*    ew   = (uint2*)(offs + (N+4));               // E

    hipMemsetAsync(cnt, 0, (size_t)2*N*sizeof(unsigned), stream);

    k_prep   <<<65, 256, 0, stream>>>(Waw, Wab, a, v, W1w, W2w, W1c, W2c);
    k_msg    <<<512, 256, 0, stream>>>(F, W1c, W1b, Hp, N);
    k_scal   <<<(N+3)/4, 256, 0, stream>>>(F, v, ss, sd, N);
    k_hist   <<<(E+255)/256, 256, 0, stream>>>(dstp, cnt, E);
    k_scan   <<<(N+1+1023)/1024, 256, 0, stream>>>(cnt, offs, N);
    k_scatter<<<(E+255)/256, 256, 0, stream>>>(srcp, dstp, offs, cur, ss, sd, ew, E);
    k_gather <<<(N+3)/4, 256, 0, stream>>>(offs, ew, Hp, out, N);
    k_final  <<<512, 256, 0, stream>>>(F, W2c, W2b, out, N);
}

// Round 4
// 290.931 us; speedup vs baseline: 2.1298x; 1.2284x over previous
//
#include <hip/hip_runtime.h>

#define D 128
typedef __attribute__((ext_vector_type(8))) short short8;
typedef __attribute__((ext_vector_type(4))) float f32x4;

__device__ __forceinline__ float leaky(float x){ return x >= 0.f ? x : 0.01f*x; }
__device__ __forceinline__ unsigned short f2bf(float x){
    unsigned u = __float_as_uint(x);
    u = (u + 0x7fffu + ((u>>16)&1u)) >> 16;
    return (unsigned short)u;
}

// fold attention vectors + convert W1/W2 to bf16 + zero cnt
__global__ void k_prep(const float* __restrict__ Ww, const float* __restrict__ Wb,
                       const float* __restrict__ a, float* __restrict__ v,
                       const float* __restrict__ W1, const float* __restrict__ W2,
                       unsigned short* __restrict__ W1b, unsigned short* __restrict__ W2b,
                       unsigned* __restrict__ cnt, int N){
    int b = blockIdx.x;
    int nz = (N+255)>>8;
    if(b < nz){ int i = b*256 + threadIdx.x; if(i<N) cnt[i]=0u; return; }
    b -= nz;
    if(b < 64){
        int i = b*256 + threadIdx.x; // 0..16383
        W1b[i] = f2bf(W1[i]);
        W2b[i] = f2bf(W2[i]);
        return;
    }
    int i = threadIdx.x; if(i >= 128) return;
    float vs=0.f, vd=0.f;
    for (int o=0;o<D;++o){ float w = Ww[o*D+i]; vs = fmaf(w, a[o], vs); vd = fmaf(w, a[D+o], vd); }
    v[i]=vs; v[D+i]=vd;
    if(i==0){
        float cs=0.f,cd=0.f;
        for(int o=0;o<D;++o){ cs=fmaf(Wb[o],a[o],cs); cd=fmaf(Wb[o],a[D+o],cd); }
        v[256]=cs; v[257]=cd;
    }
}

// Fused: H_perm = bf16(F @ W1^T + b1) (permuted rows c' = (c&15)*8 + (c>>4))
//        + per-node attention scalars ss/sd from the same F registers
__global__ __launch_bounds__(256) void k_msgscal(const float* __restrict__ F,
        const unsigned short* __restrict__ W1b, const float* __restrict__ b1,
        const float* __restrict__ v, unsigned short* __restrict__ Hp,
        float* __restrict__ ss, float* __restrict__ sd, int N){
    const int lane = threadIdx.x & 63;
    const int wid  = blockIdx.x*4 + (threadIdx.x>>6);
    const int nw   = gridDim.x*4;
    const int t = lane & 15, g = lane >> 4;
    short8 wf[4][8];
    #pragma unroll
    for(int kk=0;kk<4;++kk)
      #pragma unroll
      for(int j=0;j<8;++j)
        wf[kk][j] = *(const short8*)(W1b + (size_t)(j*16+t)*D + kk*32 + g*8);
    float bb[8];
    #pragma unroll
    for(int j=0;j<8;++j) bb[j] = b1[j*16+t];
    const float c_s = v[256], c_d = v[257];
    const int Mt = (N+15)>>4;
    for(int rt = wid; rt < Mt; rt += nw){
        int row0 = rt*16 + t;
        int row = row0 < N ? row0 : N-1;
        const float* fr = F + (size_t)row*D + g*8;
        f32x4 acc[8];
        #pragma unroll
        for(int j=0;j<8;++j) acc[j] = (f32x4){0.f,0.f,0.f,0.f};
        float ds = 0.f, dd = 0.f;
        #pragma unroll
        for(int kk=0;kk<4;++kk){
            f32x4 lo = *(const f32x4*)(fr + kk*32);
            f32x4 hi = *(const f32x4*)(fr + kk*32 + 4);
            f32x4 vsl = *(const f32x4*)(v + kk*32 + g*8);
            f32x4 vsh = *(const f32x4*)(v + kk*32 + g*8 + 4);
            f32x4 vdl = *(const f32x4*)(v + D + kk*32 + g*8);
            f32x4 vdh = *(const f32x4*)(v + D + kk*32 + g*8 + 4);
            #pragma unroll
            for(int q=0;q<4;++q){
                ds = fmaf(lo[q], vsl[q], ds); ds = fmaf(hi[q], vsh[q], ds);
                dd = fmaf(lo[q], vdl[q], dd); dd = fmaf(hi[q], vdh[q], dd);
            }
            short8 af;
            af[0]=(short)f2bf(lo[0]); af[1]=(short)f2bf(lo[1]);
            af[2]=(short)f2bf(lo[2]); af[3]=(short)f2bf(lo[3]);
            af[4]=(short)f2bf(hi[0]); af[5]=(short)f2bf(hi[1]);
            af[6]=(short)f2bf(hi[2]); af[7]=(short)f2bf(hi[3]);
            #pragma unroll
            for(int j=0;j<8;++j)
                acc[j] = __builtin_amdgcn_mfma_f32_16x16x32_bf16(af, wf[kk][j], acc[j], 0,0,0);
        }
        // attention scalars: reduce 4 column-groups
        ds += __shfl_xor(ds,16); ds += __shfl_xor(ds,32);
        dd += __shfl_xor(dd,16); dd += __shfl_xor(dd,32);
        if(g==0 && row0 < N){ ss[row0] = ds + c_s; sd[row0] = dd + c_d; }
        #pragma unroll
        for(int r=0;r<4;++r){
            int rr = rt*16 + g*4 + r;
            if(rr < N){
                short8 h;
                #pragma unroll
                for(int j=0;j<8;++j) h[j] = (short)f2bf(acc[j][r] + bb[j]);
                *(short8*)(Hp + (size_t)rr*D + t*8) = h;
            }
        }
    }
}

// per-edge: rank via atomic, exp-weight computed once, both stored coalesced
__global__ void k_hist(const int* __restrict__ src, const int* __restrict__ dst,
                       const float* __restrict__ ss, const float* __restrict__ sd,
                       unsigned* __restrict__ cnt, unsigned* __restrict__ rank,
                       float* __restrict__ wv, int E){
    int e = blockIdx.x*blockDim.x + threadIdx.x;
    if(e>=E) return;
    int d = dst[e], s = src[e];
    wv[e] = __expf(leaky(ss[s] + sd[d]));
    rank[e] = atomicAdd(&cnt[d], 1u);
}

// exclusive scan, 1024 elems/block; block prefix by redundant reduce (no inter-block dep)
__global__ void k_scan(const unsigned* __restrict__ cnt, unsigned* __restrict__ off, int N){
    int b = blockIdx.x, t = threadIdx.x; // 256 threads
    int base = b*1024;
    __shared__ unsigned lds[256];
    unsigned s = 0;
    for(int j=t; j<base; j+=256) s += cnt[j];
    #pragma unroll
    for(int o=1;o<64;o<<=1) s += __shfl_xor(s,o);
    if((t&63)==0) lds[t>>6] = s;
    __syncthreads();
    unsigned prefix = lds[0]+lds[1]+lds[2]+lds[3];
    __syncthreads();
    unsigned v[4]; unsigned tsum=0;
    #pragma unroll
    for(int k=0;k<4;++k){ int i = base + t*4 + k; v[k] = (i<N)?cnt[i]:0u; tsum += v[k]; }
    unsigned x = tsum;
    #pragma unroll
    for(int o=1;o<64;o<<=1){ unsigned y = __shfl_up(x,(unsigned)o); if((t&63)>=o) x += y; }
    if((t&63)==63) lds[t>>6] = x;
    __syncthreads();
    unsigned waveoff = 0;
    for(int w=0; w<(t>>6); ++w) waveoff += lds[w];
    unsigned run = prefix + waveoff + (x - tsum);
    #pragma unroll
    for(int k=0;k<4;++k){
        int i = base + t*4 + k;
        if(i<N) off[i] = run;
        else if(i==N) off[N] = run;
        run += v[k];
    }
}

// atomic-free scatter into CSR slots
__global__ void k_scatter(const int* __restrict__ src, const int* __restrict__ dst,
                          const unsigned* __restrict__ off, const unsigned* __restrict__ rank,
                          const float* __restrict__ wv, uint2* __restrict__ ew, int E){
    int e = blockIdx.x*blockDim.x + threadIdx.x;
    if(e>=E) return;
    unsigned p = off[dst[e]] + rank[e];
    ew[p] = make_uint2((unsigned)src[e], __float_as_uint(wv[e]));
}

// fused gather: 4 edges/iter, 16 lanes/edge, 16B per lane; online denominator.
__global__ __launch_bounds__(256) void k_gather(const unsigned* __restrict__ off,
        const uint2* __restrict__ ew, const unsigned short* __restrict__ Hp,
        float* __restrict__ out, int N){
    const int wv = threadIdx.x>>6, l = threadIdx.x&63;
    const int d = blockIdx.x*4 + wv;
    if(d>=N) return;
    const int g = l>>4, t = l&15;
    const unsigned kb = off[d], ke = off[d+1];
    float acc[8];
    #pragma unroll
    for(int j=0;j<8;++j) acc[j]=0.f;
    float den = 0.f;

    unsigned e = kb + g;
    bool v = e < ke;
    uint2 sw = make_uint2(0u,0u);
    uint4 u  = make_uint4(0u,0u,0u,0u);
    if(v){
        sw = ew[e];
        u  = *(const uint4*)(Hp + (size_t)sw.x*D + t*8);
    }
    while(v){
        unsigned e2 = e + 4;
        bool v2 = e2 < ke;
        uint2 sw2 = make_uint2(0u,0u);
        uint4 u2  = make_uint4(0u,0u,0u,0u);
        if(v2){
            sw2 = ew[e2];
            u2  = *(const uint4*)(Hp + (size_t)sw2.x*D + t*8);
        }
        float w = __uint_as_float(sw.y);
        acc[0] = fmaf(w, __uint_as_float(u.x<<16),        acc[0]);
        acc[1] = fmaf(w, __uint_as_float(u.x&0xffff0000u),acc[1]);
        acc[2] = fmaf(w, __uint_as_float(u.y<<16),        acc[2]);
        acc[3] = fmaf(w, __uint_as_float(u.y&0xffff0000u),acc[3]);
        acc[4] = fmaf(w, __uint_as_float(u.z<<16),        acc[4]);
        acc[5] = fmaf(w, __uint_as_float(u.z&0xffff0000u),acc[5]);
        acc[6] = fmaf(w, __uint_as_float(u.w<<16),        acc[6]);
        acc[7] = fmaf(w, __uint_as_float(u.w&0xffff0000u),acc[7]);
        den += w;
        v = v2; sw = sw2; u = u2; e = e2;
    }
    #pragma unroll
    for(int j=0;j<8;++j){
        acc[j] += __shfl_xor(acc[j],16);
        acc[j] += __shfl_xor(acc[j],32);
    }
    den += __shfl_xor(den,16);
    den += __shfl_xor(den,32);
    float inv = 1.f/(den + 1e-9f);
    int c = g*32 + t;
    out[(size_t)d*D + c]      = acc[g*2]  * inv;
    out[(size_t)d*D + c + 16] = acc[g*2+1]* inv;
}

// out = leaky(f + h + (f*h)@W2^T + b2), in place on out (h currently in out)
__global__ __launch_bounds__(256) void k_final(const float* __restrict__ F,
        const unsigned short* __restrict__ W2b, const float* __restrict__ b2,
        float* __restrict__ out, int N){
    const int lane = threadIdx.x & 63;
    const int wid  = blockIdx.x*4 + (threadIdx.x>>6);
    const int nw   = gridDim.x*4;
    const int t = lane & 15, g = lane >> 4;
    short8 wf[4][8];
    #pragma unroll
    for(int kk=0;kk<4;++kk)
      #pragma unroll
      for(int j=0;j<8;++j)
        wf[kk][j] = *(const short8*)(W2b + (size_t)(j*16+t)*D + kk*32 + g*8);
    float bb[8];
    #pragma unroll
    for(int j=0;j<8;++j) bb[j] = b2[j*16+t];
    const int Mt = (N+15)>>4;
    for(int rt = wid; rt < Mt; rt += nw){
        int row = rt*16 + t; if(row>=N) row = N-1;
        const float* fr = F   + (size_t)row*D + g*8;
        const float* hr = out + (size_t)row*D + g*8;
        f32x4 acc[8];
        #pragma unroll
        for(int j=0;j<8;++j) acc[j] = (f32x4){0.f,0.f,0.f,0.f};
        #pragma unroll
        for(int kk=0;kk<4;++kk){
            f32x4 flo = *(const f32x4*)(fr + kk*32);
            f32x4 fhi = *(const f32x4*)(fr + kk*32 + 4);
            f32x4 hlo = *(const f32x4*)(hr + kk*32);
            f32x4 hhi = *(const f32x4*)(hr + kk*32 + 4);
            short8 af;
            af[0]=(short)f2bf(flo[0]*hlo[0]); af[1]=(short)f2bf(flo[1]*hlo[1]);
            af[2]=(short)f2bf(flo[2]*hlo[2]); af[3]=(short)f2bf(flo[3]*hlo[3]);
            af[4]=(short)f2bf(fhi[0]*hhi[0]); af[5]=(short)f2bf(fhi[1]*hhi[1]);
            af[6]=(short)f2bf(fhi[2]*hhi[2]); af[7]=(short)f2bf(fhi[3]*hhi[3]);
            #pragma unroll
            for(int j=0;j<8;++j)
                acc[j] = __builtin_amdgcn_mfma_f32_16x16x32_bf16(af, wf[kk][j], acc[j], 0,0,0);
        }
        #pragma unroll
        for(int r=0;r<4;++r){
            int rr = rt*16 + g*4 + r;
            if(rr < N){
                #pragma unroll
                for(int j=0;j<8;++j){
                    int c = j*16 + t;
                    float f = F[(size_t)rr*D + c];
                    float h = out[(size_t)rr*D + c];
                    float val = f + h + acc[j][r] + bb[j];
                    out[(size_t)rr*D + c] = leaky(val);
                }
            }
        }
    }
}

extern "C" void kernel_launch(void* const* d_in, const int* in_sizes, int n_in,
                              void* d_out, int out_size, void* d_ws, size_t ws_size,
                              hipStream_t stream) {
    const int*   idx  = (const int*)  d_in[0];   // (2,E)
    const float* F    = (const float*)d_in[1];   // (N,128)
    const float* Waw  = (const float*)d_in[3];
    const float* Wab  = (const float*)d_in[4];
    const float* W1w  = (const float*)d_in[5];
    const float* W1b  = (const float*)d_in[6];
    const float* W2w  = (const float*)d_in[7];
    const float* W2b  = (const float*)d_in[8];
    const float* a    = (const float*)d_in[9];
    float* out = (float*)d_out;

    const int E = in_sizes[0]/2;
    const int N = in_sizes[1]/D;
    const int* srcp = idx;
    const int* dstp = idx + E;

    unsigned short* Hp  = (unsigned short*)d_ws;           // N*128 bf16 (permuted rows)
    unsigned short* W1c = Hp + (size_t)N*D;                // 16384
    unsigned short* W2c = W1c + 16384;                     // 16384
    float*    ss   = (float*)(W2c + 16384);                // N
    float*    sd   = ss + N;                               // N
    float*    v    = sd + N;                               // 320
    unsigned* cnt  = (unsigned*)(v + 320);                 // N
    unsigned* offs = cnt + N;                              // N+4
    unsigned* rank = offs + (N+4);                         // E
    float*    wv   = (float*)(rank + E);                   // E
    uint2*    ew   = (uint2*)(wv + E);                     // E

    const int nz = (N+255)/256;

    k_prep   <<<nz+65, 256, 0, stream>>>(Waw, Wab, a, v, W1w, W2w, W1c, W2c, cnt, N);
    k_msgscal<<<512, 256, 0, stream>>>(F, W1c, W1b, v, Hp, ss, sd, N);
    k_hist   <<<(E+255)/256, 256, 0, stream>>>(srcp, dstp, ss, sd, cnt, rank, wv, E);
    k_scan   <<<(N+1+1023)/1024, 256, 0, stream>>>(cnt, offs, N);
    k_scatter<<<(E+255)/256, 256, 0, stream>>>(srcp, dstp, offs, rank, wv, ew, E);
    k_gather <<<(N+3)/4, 256, 0, stream>>>(offs, ew, Hp, out, N);
    k_final  <<<512, 256, 0, stream>>>(F, W2c, W2b, out, N);
}

// Round 5
// 283.635 us; speedup vs baseline: 2.1846x; 1.0257x over previous
//
#include <hip/hip_runtime.h>

#define D 128
typedef __attribute__((ext_vector_type(8))) short short8;
typedef __attribute__((ext_vector_type(4))) float f32x4;

__device__ __forceinline__ float leaky(float x){ return x >= 0.f ? x : 0.01f*x; }
__device__ __forceinline__ unsigned short f2bf(float x){
    unsigned u = __float_as_uint(x);
    u = (u + 0x7fffu + ((u>>16)&1u)) >> 16;
    return (unsigned short)u;
}

// fold attention vectors + convert W1/W2 to bf16 + zero cnt
__global__ void k_prep(const float* __restrict__ Ww, const float* __restrict__ Wb,
                       const float* __restrict__ a, float* __restrict__ v,
                       const float* __restrict__ W1, const float* __restrict__ W2,
                       unsigned short* __restrict__ W1b, unsigned short* __restrict__ W2b,
                       unsigned* __restrict__ cnt, int N){
    int b = blockIdx.x;
    int nz = (N+255)>>8;
    if(b < nz){ int i = b*256 + threadIdx.x; if(i<N) cnt[i]=0u; return; }
    b -= nz;
    if(b < 64){
        int i = b*256 + threadIdx.x; // 0..16383
        W1b[i] = f2bf(W1[i]);
        W2b[i] = f2bf(W2[i]);
        return;
    }
    int i = threadIdx.x; if(i >= 128) return;
    float vs=0.f, vd=0.f;
    for (int o=0;o<D;++o){ float w = Ww[o*D+i]; vs = fmaf(w, a[o], vs); vd = fmaf(w, a[D+o], vd); }
    v[i]=vs; v[D+i]=vd;
    if(i==0){
        float cs=0.f,cd=0.f;
        for(int o=0;o<D;++o){ cs=fmaf(Wb[o],a[o],cs); cd=fmaf(Wb[o],a[D+o],cd); }
        v[256]=cs; v[257]=cd;
    }
}

// Fused: [blocks < GB]  H_perm = bf16(F @ W1^T + b1) (permuted c' = (c&15)*8 + (c>>4))
//                       + per-node attention scalars ss/sd
//        [blocks >= GB] edge rank histogram (atomics hidden under GEMM)
__global__ __launch_bounds__(256) void k_msgscal(const float* __restrict__ F,
        const unsigned short* __restrict__ W1b, const float* __restrict__ b1,
        const float* __restrict__ v, unsigned short* __restrict__ Hp,
        float* __restrict__ ss, float* __restrict__ sd, int N,
        const int* __restrict__ dst, unsigned* __restrict__ cnt,
        unsigned* __restrict__ rank, int E, int GB){
    if((int)blockIdx.x >= GB){
        int e = ((int)blockIdx.x - GB)*256 + (int)threadIdx.x;
        if(e < E) rank[e] = atomicAdd(&cnt[dst[e]], 1u);
        return;
    }
    const int lane = threadIdx.x & 63;
    const int wid  = blockIdx.x*4 + (threadIdx.x>>6);
    const int nw   = GB*4;
    const int t = lane & 15, g = lane >> 4;
    short8 wf[4][8];
    #pragma unroll
    for(int kk=0;kk<4;++kk)
      #pragma unroll
      for(int j=0;j<8;++j)
        wf[kk][j] = *(const short8*)(W1b + (size_t)(j*16+t)*D + kk*32 + g*8);
    float bb[8];
    #pragma unroll
    for(int j=0;j<8;++j) bb[j] = b1[j*16+t];
    const float c_s = v[256], c_d = v[257];
    const int Mt = (N+15)>>4;
    for(int rt = wid; rt < Mt; rt += nw){
        int row0 = rt*16 + t;
        int row = row0 < N ? row0 : N-1;
        const float* fr = F + (size_t)row*D + g*8;
        f32x4 acc[8];
        #pragma unroll
        for(int j=0;j<8;++j) acc[j] = (f32x4){0.f,0.f,0.f,0.f};
        float ds = 0.f, dd = 0.f;
        #pragma unroll
        for(int kk=0;kk<4;++kk){
            f32x4 lo = *(const f32x4*)(fr + kk*32);
            f32x4 hi = *(const f32x4*)(fr + kk*32 + 4);
            f32x4 vsl = *(const f32x4*)(v + kk*32 + g*8);
            f32x4 vsh = *(const f32x4*)(v + kk*32 + g*8 + 4);
            f32x4 vdl = *(const f32x4*)(v + D + kk*32 + g*8);
            f32x4 vdh = *(const f32x4*)(v + D + kk*32 + g*8 + 4);
            #pragma unroll
            for(int q=0;q<4;++q){
                ds = fmaf(lo[q], vsl[q], ds); ds = fmaf(hi[q], vsh[q], ds);
                dd = fmaf(lo[q], vdl[q], dd); dd = fmaf(hi[q], vdh[q], dd);
            }
            short8 af;
            af[0]=(short)f2bf(lo[0]); af[1]=(short)f2bf(lo[1]);
            af[2]=(short)f2bf(lo[2]); af[3]=(short)f2bf(lo[3]);
            af[4]=(short)f2bf(hi[0]); af[5]=(short)f2bf(hi[1]);
            af[6]=(short)f2bf(hi[2]); af[7]=(short)f2bf(hi[3]);
            #pragma unroll
            for(int j=0;j<8;++j)
                acc[j] = __builtin_amdgcn_mfma_f32_16x16x32_bf16(af, wf[kk][j], acc[j], 0,0,0);
        }
        ds += __shfl_xor(ds,16); ds += __shfl_xor(ds,32);
        dd += __shfl_xor(dd,16); dd += __shfl_xor(dd,32);
        if(g==0 && row0 < N){ ss[row0] = ds + c_s; sd[row0] = dd + c_d; }
        #pragma unroll
        for(int r=0;r<4;++r){
            int rr = rt*16 + g*4 + r;
            if(rr < N){
                short8 h;
                #pragma unroll
                for(int j=0;j<8;++j) h[j] = (short)f2bf(acc[j][r] + bb[j]);
                *(short8*)(Hp + (size_t)rr*D + t*8) = h;
            }
        }
    }
}

// exclusive scan, 1024 elems/block; block prefix by redundant reduce (no inter-block dep)
__global__ void k_scan(const unsigned* __restrict__ cnt, unsigned* __restrict__ off, int N){
    int b = blockIdx.x, t = threadIdx.x; // 256 threads
    int base = b*1024;
    __shared__ unsigned lds[256];
    unsigned s = 0;
    for(int j=t; j<base; j+=256) s += cnt[j];
    #pragma unroll
    for(int o=1;o<64;o<<=1) s += __shfl_xor(s,o);
    if((t&63)==0) lds[t>>6] = s;
    __syncthreads();
    unsigned prefix = lds[0]+lds[1]+lds[2]+lds[3];
    __syncthreads();
    unsigned v[4]; unsigned tsum=0;
    #pragma unroll
    for(int k=0;k<4;++k){ int i = base + t*4 + k; v[k] = (i<N)?cnt[i]:0u; tsum += v[k]; }
    unsigned x = tsum;
    #pragma unroll
    for(int o=1;o<64;o<<=1){ unsigned y = __shfl_up(x,(unsigned)o); if((t&63)>=o) x += y; }
    if((t&63)==63) lds[t>>6] = x;
    __syncthreads();
    unsigned waveoff = 0;
    for(int w=0; w<(t>>6); ++w) waveoff += lds[w];
    unsigned run = prefix + waveoff + (x - tsum);
    #pragma unroll
    for(int k=0;k<4;++k){
        int i = base + t*4 + k;
        if(i<N) off[i] = run;
        else if(i==N) off[N] = run;
        run += v[k];
    }
}

// atomic-free scatter: place src id into CSR slot (4B random store)
__global__ void k_scatter(const int* __restrict__ src, const int* __restrict__ dst,
                          const unsigned* __restrict__ off, const unsigned* __restrict__ rank,
                          unsigned* __restrict__ esrc, int E){
    int e = blockIdx.x*blockDim.x + threadIdx.x;
    if(e>=E) return;
    esrc[off[dst[e]] + rank[e]] = (unsigned)src[e];
}

// fused gather: 4 edges/iter, 16 lanes/edge, 16B/lane; w computed in-kernel;
// 2-deep software pipeline (8 rows in flight per wave)
__global__ __launch_bounds__(256) void k_gather(const unsigned* __restrict__ off,
        const unsigned* __restrict__ esrc, const float* __restrict__ ss,
        const float* __restrict__ sdv, const unsigned short* __restrict__ Hp,
        float* __restrict__ out, int N){
    const int wv = threadIdx.x>>6, l = threadIdx.x&63;
    const int d = blockIdx.x*4 + wv;
    if(d>=N) return;
    const int g = l>>4, t = l&15;
    const unsigned kb = off[d], ke = off[d+1];
    const float sdd = sdv[d];
    float acc[8];
    #pragma unroll
    for(int j=0;j<8;++j) acc[j]=0.f;
    float den = 0.f;

    unsigned eA = kb + g;
    unsigned eB = eA + 4;
    bool vA = eA < ke, vB = eB < ke;
    float ssA=0.f, ssB=0.f;
    uint4 uA = make_uint4(0u,0u,0u,0u), uB = make_uint4(0u,0u,0u,0u);
    if(vA){ unsigned s=esrc[eA]; ssA=ss[s]; uA=*(const uint4*)(Hp+(size_t)s*D+t*8); }
    if(vB){ unsigned s=esrc[eB]; ssB=ss[s]; uB=*(const uint4*)(Hp+(size_t)s*D+t*8); }
    while(vA){
        unsigned eC = eB + 4;
        bool vC = eC < ke;
        float ssC = 0.f; uint4 uC = make_uint4(0u,0u,0u,0u);
        if(vC){ unsigned s=esrc[eC]; ssC=ss[s]; uC=*(const uint4*)(Hp+(size_t)s*D+t*8); }
        float w = __expf(leaky(ssA + sdd));
        acc[0] = fmaf(w, __uint_as_float(uA.x<<16),        acc[0]);
        acc[1] = fmaf(w, __uint_as_float(uA.x&0xffff0000u),acc[1]);
        acc[2] = fmaf(w, __uint_as_float(uA.y<<16),        acc[2]);
        acc[3] = fmaf(w, __uint_as_float(uA.y&0xffff0000u),acc[3]);
        acc[4] = fmaf(w, __uint_as_float(uA.z<<16),        acc[4]);
        acc[5] = fmaf(w, __uint_as_float(uA.z&0xffff0000u),acc[5]);
        acc[6] = fmaf(w, __uint_as_float(uA.w<<16),        acc[6]);
        acc[7] = fmaf(w, __uint_as_float(uA.w&0xffff0000u),acc[7]);
        den += w;
        vA = vB; ssA = ssB; uA = uB;
        vB = vC; ssB = ssC; uB = uC;
        eB = eC;
    }
    #pragma unroll
    for(int j=0;j<8;++j){
        acc[j] += __shfl_xor(acc[j],16);
        acc[j] += __shfl_xor(acc[j],32);
    }
    den += __shfl_xor(den,16);
    den += __shfl_xor(den,32);
    float inv = 1.f/(den + 1e-9f);
    int c = g*32 + t;
    out[(size_t)d*D + c]      = acc[g*2]  * inv;
    out[(size_t)d*D + c + 16] = acc[g*2+1]* inv;
}

// out = leaky(f + h + (f*h)@W2^T + b2), in place on out (h currently in out)
__global__ __launch_bounds__(256) void k_final(const float* __restrict__ F,
        const unsigned short* __restrict__ W2b, const float* __restrict__ b2,
        float* __restrict__ out, int N){
    const int lane = threadIdx.x & 63;
    const int wid  = blockIdx.x*4 + (threadIdx.x>>6);
    const int nw   = gridDim.x*4;
    const int t = lane & 15, g = lane >> 4;
    short8 wf[4][8];
    #pragma unroll
    for(int kk=0;kk<4;++kk)
      #pragma unroll
      for(int j=0;j<8;++j)
        wf[kk][j] = *(const short8*)(W2b + (size_t)(j*16+t)*D + kk*32 + g*8);
    float bb[8];
    #pragma unroll
    for(int j=0;j<8;++j) bb[j] = b2[j*16+t];
    const int Mt = (N+15)>>4;
    for(int rt = wid; rt < Mt; rt += nw){
        int row = rt*16 + t; if(row>=N) row = N-1;
        const float* fr = F   + (size_t)row*D + g*8;
        const float* hr = out + (size_t)row*D + g*8;
        f32x4 acc[8];
        #pragma unroll
        for(int j=0;j<8;++j) acc[j] = (f32x4){0.f,0.f,0.f,0.f};
        #pragma unroll
        for(int kk=0;kk<4;++kk){
            f32x4 flo = *(const f32x4*)(fr + kk*32);
            f32x4 fhi = *(const f32x4*)(fr + kk*32 + 4);
            f32x4 hlo = *(const f32x4*)(hr + kk*32);
            f32x4 hhi = *(const f32x4*)(hr + kk*32 + 4);
            short8 af;
            af[0]=(short)f2bf(flo[0]*hlo[0]); af[1]=(short)f2bf(flo[1]*hlo[1]);
            af[2]=(short)f2bf(flo[2]*hlo[2]); af[3]=(short)f2bf(flo[3]*hlo[3]);
            af[4]=(short)f2bf(fhi[0]*hhi[0]); af[5]=(short)f2bf(fhi[1]*hhi[1]);
            af[6]=(short)f2bf(fhi[2]*hhi[2]); af[7]=(short)f2bf(fhi[3]*hhi[3]);
            #pragma unroll
            for(int j=0;j<8;++j)
                acc[j] = __builtin_amdgcn_mfma_f32_16x16x32_bf16(af, wf[kk][j], acc[j], 0,0,0);
        }
        #pragma unroll
        for(int r=0;r<4;++r){
            int rr = rt*16 + g*4 + r;
            if(rr < N){
                #pragma unroll
                for(int j=0;j<8;++j){
                    int c = j*16 + t;
                    float f = F[(size_t)rr*D + c];
                    float h = out[(size_t)rr*D + c];
                    float val = f + h + acc[j][r] + bb[j];
                    out[(size_t)rr*D + c] = leaky(val);
                }
            }
        }
    }
}

extern "C" void kernel_launch(void* const* d_in, const int* in_sizes, int n_in,
                              void* d_out, int out_size, void* d_ws, size_t ws_size,
                              hipStream_t stream) {
    const int*   idx  = (const int*)  d_in[0];   // (2,E)
    const float* F    = (const float*)d_in[1];   // (N,128)
    const float* Waw  = (const float*)d_in[3];
    const float* Wab  = (const float*)d_in[4];
    const float* W1w  = (const float*)d_in[5];
    const float* W1b  = (const float*)d_in[6];
    const float* W2w  = (const float*)d_in[7];
    const float* W2b  = (const float*)d_in[8];
    const float* a    = (const float*)d_in[9];
    float* out = (float*)d_out;

    const int E = in_sizes[0]/2;
    const int N = in_sizes[1]/D;
    const int* srcp = idx;
    const int* dstp = idx + E;

    unsigned short* Hp  = (unsigned short*)d_ws;           // N*128 bf16 (permuted rows)
    unsigned short* W1c = Hp + (size_t)N*D;                // 16384
    unsigned short* W2c = W1c + 16384;                     // 16384
    float*    ss   = (float*)(W2c + 16384);                // N
    float*    sd   = ss + N;                               // N
    float*    v    = sd + N;                               // 320
    unsigned* cnt  = (unsigned*)(v + 320);                 // N
    unsigned* offs = cnt + N;                              // N+4
    unsigned* rank = offs + (N+4);                         // E
    unsigned* esrc = rank + E;                             // E

    const int nz = (N+255)/256;
    const int GB = 512;
    const int EB = (E+255)/256;

    k_prep   <<<nz+65, 256, 0, stream>>>(Waw, Wab, a, v, W1w, W2w, W1c, W2c, cnt, N);
    k_msgscal<<<GB+EB, 256, 0, stream>>>(F, W1c, W1b, v, Hp, ss, sd, N, dstp, cnt, rank, E, GB);
    k_scan   <<<(N+1+1023)/1024, 256, 0, stream>>>(cnt, offs, N);
    k_scatter<<<EB, 256, 0, stream>>>(srcp, dstp, offs, rank, esrc, E);
    k_gather <<<(N+3)/4, 256, 0, stream>>>(offs, esrc, ss, sd, Hp, out, N);
    k_final  <<<512, 256, 0, stream>>>(F, W2c, W2b, out, N);
}